// Round 11
// baseline (912.200 us; speedup 1.0000x reference)
//
#include <hip/hip_runtime.h>

typedef unsigned short ushort_t;
typedef unsigned int uint_t;

typedef __attribute__((ext_vector_type(8))) __bf16 bf16x8_t;
typedef __attribute__((ext_vector_type(8))) short s16x8;
typedef __attribute__((ext_vector_type(4))) float f32x4;

#define T_TOK 2048
#define H_DIM 2048
#define I_DIM 1024
#define N_EXP 64
#define TOPK 8
#define MT 6         // 128-row m-tiles: covers up to 768 tokens/expert (mean 256)
#define LSTR 40      // LDS row stride in bf16 elems (BK=32 + 8 pad) — R4-proven

// Raw barrier: does NOT drain vmcnt -> in-flight global loads stay outstanding.
#define BAR_RAW()  asm volatile("s_barrier" ::: "memory")
// LDS-visibility barrier: drain ds ops (lgkm) then barrier; vmcnt untouched.
#define BAR_LGKM() asm volatile("s_waitcnt lgkmcnt(0)\n\ts_barrier" ::: "memory")

__device__ inline f32x4 mfma_bf16(s16x8 a, s16x8 b, f32x4 c) {
  return __builtin_amdgcn_mfma_f32_16x16x32_bf16(
      __builtin_bit_cast(bf16x8_t, a), __builtin_bit_cast(bf16x8_t, b), c, 0, 0, 0);
}

__device__ inline ushort_t f2bf(float f) {
  uint_t u = __float_as_uint(f);
  u += 0x7FFFu + ((u >> 16) & 1u);   // round-to-nearest-even
  return (ushort_t)(u >> 16);
}
__device__ inline float bf2f(ushort_t h) {
  return __uint_as_float(((uint_t)h) << 16);
}

// packed f32x2 -> bf16x2 (RNE), 1 instruction
__device__ inline uint_t pkbf(float a, float b) {
  uint_t r;
  asm("v_cvt_pk_bf16_f32 %0, %1, %2" : "=v"(r) : "v"(a), "v"(b));
  return r;
}
// float4 -> 4 bf16 (8 B)
__device__ inline uint2 pk4(float4 v) {
  uint2 w;
  w.x = pkbf(v.x, v.y);
  w.y = pkbf(v.z, v.w);
  return w;
}

// XCD-chunk swizzle (bijective when nwg % 8 == 0)
__device__ __forceinline__ int xcd_swizzle(int bid, int nwg) {
  int q = nwg >> 3;
  return (bid & 7) * q + (bid >> 3);
}

// ---------------- Router: logits[t][e] = sum_h x[t][h] * gw[e][h] (fp32 exact) ----------
__global__ __launch_bounds__(256) void router_kernel(const float* __restrict__ X,
                                                     const float* __restrict__ GW,
                                                     float* __restrict__ logits) {
  __shared__ float xs[4][H_DIM];
  int tid = threadIdx.x;
  int t0 = blockIdx.x * 4;
  const float4* src = (const float4*)(X + (size_t)t0 * H_DIM);
  float4* dst = (float4*)(&xs[0][0]);
#pragma unroll
  for (int j = 0; j < 8; ++j) dst[tid + 256 * j] = src[tid + 256 * j];
  __syncthreads();
  int wave = tid >> 6, lane = tid & 63;
  int t = t0 + wave;
  const float4* w = (const float4*)(GW + (size_t)lane * H_DIM);
  const float4* xr = (const float4*)(&xs[wave][0]);
  float acc = 0.f;
  for (int i = 0; i < H_DIM / 4; ++i) {
    float4 a = xr[i];
    float4 b = w[i];
    acc = fmaf(a.x, b.x, acc);
    acc = fmaf(a.y, b.y, acc);
    acc = fmaf(a.z, b.z, acc);
    acc = fmaf(a.w, b.w, acc);
  }
  logits[(size_t)t * N_EXP + lane] = acc;
}

// ---------------- Softmax + top-8 per token (one wave per token) -----------------------
__global__ __launch_bounds__(256) void topk_kernel(const float* __restrict__ logits,
                                                   int* __restrict__ counts,
                                                   int* __restrict__ sel_e,
                                                   float* __restrict__ sel_w) {
  int tid = threadIdx.x;
  int wave = tid >> 6, lane = tid & 63;
  int t = blockIdx.x * 4 + wave;
  float l = logits[(size_t)t * N_EXP + lane];
  float m = l;
#pragma unroll
  for (int s = 32; s; s >>= 1) m = fmaxf(m, __shfl_xor(m, s, 64));
  float p = __expf(l - m);
  float sum = p;
#pragma unroll
  for (int s = 32; s; s >>= 1) sum += __shfl_xor(sum, s, 64);
  float prob = p / sum;

  float val = l;
#pragma unroll
  for (int k = 0; k < TOPK; ++k) {
    float bv = val;
    int bi = lane;
#pragma unroll
    for (int s = 32; s; s >>= 1) {
      float ov = __shfl_xor(bv, s, 64);
      int oi = __shfl_xor(bi, s, 64);
      if (ov > bv || (ov == bv && oi < bi)) { bv = ov; bi = oi; }
    }
    float bw = __shfl(prob, bi, 64);
    if (lane == 0) {
      sel_e[t * TOPK + k] = bi;
      sel_w[t * TOPK + k] = bw;
      atomicAdd(&counts[bi], 1);
    }
    if (lane == bi) val = -INFINITY;
  }
}

// ---------------- Prefix sum over 64 expert counts -------------------------------------
__global__ void scan_kernel(const int* __restrict__ counts, int* __restrict__ offsets,
                            int* __restrict__ cursor) {
  if (threadIdx.x == 0) {
    int acc = 0;
    for (int e = 0; e < N_EXP; ++e) { offsets[e] = acc; acc += counts[e]; }
    offsets[N_EXP] = acc;
  }
  if (threadIdx.x < N_EXP) cursor[threadIdx.x] = 0;
}

// ---------------- Assign packed rows ---------------------------------------------------
__global__ __launch_bounds__(256) void assign_kernel(const int* __restrict__ sel_e,
                                                     const float* __restrict__ sel_w,
                                                     const int* __restrict__ offsets,
                                                     int* __restrict__ cursor,
                                                     int* __restrict__ token_of,
                                                     float* __restrict__ weight_of) {
  int idx = blockIdx.x * 256 + threadIdx.x;  // 0..16383
  int t = idx >> 3;
  int e = sel_e[idx];
  float w = sel_w[idx];
  int r = offsets[e] + atomicAdd(&cursor[e], 1);
  token_of[r] = t;
  weight_of[r] = w;
}

// =======================================================================================
// Projection GEMM: 512 thr, tile 128(M)x128(N), BK=32, 8 waves (2M x 4N), wave
// tile 64x32 -> acc = 8 f32x4 (32 regs). 2-deep register prefetch: tile k+2 is
// issued right after ds_write of tile k, so the implicit vmcnt wait at each
// ds_write covers loads issued TWO iterations earlier (~full HBM latency).
// Simple 2-barrier schedule (R4/R10-proven): BAR_RAW / stage / BAR_LGKM / MFMA.
// =======================================================================================

// MODE: 0 = gate (write raw g), 1 = up (read g, write silu(g)*u)
template <int MODE>
__global__ __launch_bounds__(512, 4) void proj_kernel(const float* __restrict__ X,
                                                      const float* __restrict__ W,
                                                      const int* __restrict__ offsets,
                                                      const int* __restrict__ token_of,
                                                      ushort_t* __restrict__ gact) {
  int bid = xcd_swizzle(blockIdx.x, N_EXP * MT * 8);
  int e = bid / (MT * 8);
  int mt = (bid % (MT * 8)) / 8;
  int nt = bid % 8;
  int base = offsets[e];
  int Me = offsets[e + 1] - base;
  if (mt * 128 >= Me) return;

  __shared__ ushort_t As[128 * LSTR];   // 10 KB
  __shared__ ushort_t Bs[128 * LSTR];   // 10 KB
  __shared__ int stok[128];

  int tid = threadIdx.x;
  if (tid < 128) {
    int gm = mt * 128 + tid;
    stok[tid] = token_of[base + (gm < Me ? gm : Me - 1)];
  }
  __syncthreads();

  int wave = tid >> 6, lane = tid & 63;
  int wm = wave >> 2, wn = wave & 3;

  // Staging: 4 thr/row x 128 rows; 8 floats/thread at col (tid&3)*8.
  int sr = tid >> 2, sc = (tid & 3) * 8;
  const float* pA = X + (size_t)stok[sr] * H_DIM + sc;
  const float* pB = W + ((size_t)e * I_DIM + nt * 128 + sr) * H_DIM + sc;

  f32x4 acc[4][2];
#pragma unroll
  for (int i = 0; i < 4; ++i)
#pragma unroll
    for (int j = 0; j < 2; ++j) acc[i][j] = (f32x4)0.f;

  // two prefetch sets (A even tiles, B odd tiles)
  float4 aA[2], bA[2], aB[2], bB[2];
#pragma unroll
  for (int j = 0; j < 2; ++j) {
    aA[j] = *(const float4*)(pA + 4 * j);
    bA[j] = *(const float4*)(pB + 4 * j);
    aB[j] = *(const float4*)(pA + 32 + 4 * j);
    bB[j] = *(const float4*)(pB + 32 + 4 * j);
  }

  int fr = lane & 15, q2 = lane >> 4;
  const int NK = H_DIM / 32;  // 64 (even)

#define PROJ_COMPUTE()                                                              \
  {                                                                                 \
    s16x8 af[4], bf[2];                                                             \
    _Pragma("unroll")                                                               \
    for (int mf = 0; mf < 4; ++mf)                                                  \
      af[mf] = *(const s16x8*)&As[(wm * 64 + mf * 16 + fr) * LSTR + q2 * 8];        \
    _Pragma("unroll")                                                               \
    for (int nf = 0; nf < 2; ++nf)                                                  \
      bf[nf] = *(const s16x8*)&Bs[(wn * 32 + nf * 16 + fr) * LSTR + q2 * 8];        \
    __builtin_amdgcn_s_setprio(1);                                                  \
    _Pragma("unroll")                                                               \
    for (int mf = 0; mf < 4; ++mf)                                                  \
      _Pragma("unroll")                                                             \
      for (int nf = 0; nf < 2; ++nf)                                                \
        acc[mf][nf] = mfma_bf16(af[mf], bf[nf], acc[mf][nf]);                       \
    __builtin_amdgcn_s_setprio(0);                                                  \
  }

  for (int k = 0; k < NK; k += 2) {
    // ---- even tile k (set A) ----
    BAR_RAW();
    *(uint2*)&As[sr * LSTR + sc] = pk4(aA[0]);
    *(uint2*)&As[sr * LSTR + sc + 4] = pk4(aA[1]);
    *(uint2*)&Bs[sr * LSTR + sc] = pk4(bA[0]);
    *(uint2*)&Bs[sr * LSTR + sc + 4] = pk4(bA[1]);
    if (k + 2 < NK) {
      int kn = (k + 2) * 32;
#pragma unroll
      for (int j = 0; j < 2; ++j) {
        aA[j] = *(const float4*)(pA + kn + 4 * j);
        bA[j] = *(const float4*)(pB + kn + 4 * j);
      }
    }
    BAR_LGKM();
    PROJ_COMPUTE();

    // ---- odd tile k+1 (set B) ----
    BAR_RAW();
    *(uint2*)&As[sr * LSTR + sc] = pk4(aB[0]);
    *(uint2*)&As[sr * LSTR + sc + 4] = pk4(aB[1]);
    *(uint2*)&Bs[sr * LSTR + sc] = pk4(bB[0]);
    *(uint2*)&Bs[sr * LSTR + sc + 4] = pk4(bB[1]);
    if (k + 3 < NK) {
      int kn = (k + 3) * 32;
#pragma unroll
      for (int j = 0; j < 2; ++j) {
        aB[j] = *(const float4*)(pA + kn + 4 * j);
        bB[j] = *(const float4*)(pB + kn + 4 * j);
      }
    }
    BAR_LGKM();
    PROJ_COMPUTE();
  }

  // epilogue
#pragma unroll
  for (int mf = 0; mf < 4; ++mf)
#pragma unroll
    for (int nf = 0; nf < 2; ++nf) {
      f32x4 v = acc[mf][nf];
#pragma unroll
      for (int r = 0; r < 4; ++r) {
        int gm = mt * 128 + wm * 64 + mf * 16 + q2 * 4 + r;
        if (gm < Me) {
          int col = nt * 128 + wn * 32 + nf * 16 + fr;
          size_t off = (size_t)(base + gm) * I_DIM + col;
          if (MODE == 0) {
            gact[off] = f2bf(v[r]);               // raw g
          } else {
            float gv = bf2f(gact[off]);
            float s = gv / (1.f + __expf(-gv));
            gact[off] = f2bf(s * v[r]);           // act = silu(g)*u
          }
        }
      }
    }
}

// ---------------- Down GEMM + weighted scatter to out ----------------------------------
// 512 thr, tile 128x128, BK=32, 8 waves (2Mx4N), acc = 8 f32x4; 2-deep prefetch.
__global__ __launch_bounds__(512, 4) void down_kernel(const ushort_t* __restrict__ act,
                                                      const float* __restrict__ Wd,
                                                      const int* __restrict__ offsets,
                                                      const int* __restrict__ token_of,
                                                      const float* __restrict__ weight_of,
                                                      float* __restrict__ out) {
  int bid = xcd_swizzle(blockIdx.x, N_EXP * MT * 16);
  int e = bid / (MT * 16);
  int mt = (bid % (MT * 16)) / 16;
  int nt = bid % 16;
  int base = offsets[e];
  int Me = offsets[e + 1] - base;
  if (mt * 128 >= Me) return;

  __shared__ ushort_t As[128 * LSTR];
  __shared__ ushort_t Bs[128 * LSTR];
  __shared__ int stok[128];
  __shared__ float sw[128];

  int tid = threadIdx.x;
  if (tid < 128) {
    int gm = mt * 128 + tid;
    int ok = gm < Me;
    stok[tid] = token_of[base + (ok ? gm : Me - 1)];
    sw[tid] = ok ? weight_of[base + gm] : 0.f;
  }
  __syncthreads();

  int wave = tid >> 6, lane = tid & 63;
  int wm = wave >> 2, wn = wave & 3;

  int sr = tid >> 2;
  int ac = (tid & 3) * 8;     // bf16 col (16 B / thread)
  int r0 = mt * 128 + sr;
  if (r0 >= Me) r0 = Me - 1;
  const ushort_t* pA = act + (size_t)(base + r0) * I_DIM + ac;
  int bc = (tid & 3) * 8;     // fp32 col (8 floats / thread)
  const float* pB = Wd + ((size_t)e * H_DIM + nt * 128 + sr) * I_DIM + bc;

  f32x4 acc[4][2];
#pragma unroll
  for (int i = 0; i < 4; ++i)
#pragma unroll
    for (int j = 0; j < 2; ++j) acc[i][j] = (f32x4)0.f;

  s16x8 rAa, rAb;
  float4 rBa[2], rBb[2];
  rAa = *(const s16x8*)pA;
  rAb = *(const s16x8*)(pA + 32);
#pragma unroll
  for (int j = 0; j < 2; ++j) {
    rBa[j] = *(const float4*)(pB + 4 * j);
    rBb[j] = *(const float4*)(pB + 32 + 4 * j);
  }

  int fr = lane & 15, q2 = lane >> 4;
  const int NK = I_DIM / 32;  // 32 (even)

#define DOWN_COMPUTE()                                                              \
  {                                                                                 \
    s16x8 af[4], bf[2];                                                             \
    _Pragma("unroll")                                                               \
    for (int mf = 0; mf < 4; ++mf)                                                  \
      af[mf] = *(const s16x8*)&As[(wm * 64 + mf * 16 + fr) * LSTR + q2 * 8];        \
    _Pragma("unroll")                                                               \
    for (int nf = 0; nf < 2; ++nf)                                                  \
      bf[nf] = *(const s16x8*)&Bs[(wn * 32 + nf * 16 + fr) * LSTR + q2 * 8];        \
    __builtin_amdgcn_s_setprio(1);                                                  \
    _Pragma("unroll")                                                               \
    for (int mf = 0; mf < 4; ++mf)                                                  \
      _Pragma("unroll")                                                             \
      for (int nf = 0; nf < 2; ++nf)                                                \
        acc[mf][nf] = mfma_bf16(af[mf], bf[nf], acc[mf][nf]);                       \
    __builtin_amdgcn_s_setprio(0);                                                  \
  }

  for (int k = 0; k < NK; k += 2) {
    BAR_RAW();
    *(s16x8*)&As[sr * LSTR + ac] = rAa;
    *(uint2*)&Bs[sr * LSTR + bc] = pk4(rBa[0]);
    *(uint2*)&Bs[sr * LSTR + bc + 4] = pk4(rBa[1]);
    if (k + 2 < NK) {
      int kn = (k + 2) * 32;
      rAa = *(const s16x8*)(pA + kn);
#pragma unroll
      for (int j = 0; j < 2; ++j) rBa[j] = *(const float4*)(pB + kn + 4 * j);
    }
    BAR_LGKM();
    DOWN_COMPUTE();

    BAR_RAW();
    *(s16x8*)&As[sr * LSTR + ac] = rAb;
    *(uint2*)&Bs[sr * LSTR + bc] = pk4(rBb[0]);
    *(uint2*)&Bs[sr * LSTR + bc + 4] = pk4(rBb[1]);
    if (k + 3 < NK) {
      int kn = (k + 3) * 32;
      rAb = *(const s16x8*)(pA + kn);
#pragma unroll
      for (int j = 0; j < 2; ++j) rBb[j] = *(const float4*)(pB + kn + 4 * j);
    }
    BAR_LGKM();
    DOWN_COMPUTE();
  }

#pragma unroll
  for (int mf = 0; mf < 4; ++mf)
#pragma unroll
    for (int nf = 0; nf < 2; ++nf) {
      f32x4 v = acc[mf][nf];
#pragma unroll
      for (int r = 0; r < 4; ++r) {
        int mloc = wm * 64 + mf * 16 + q2 * 4 + r;
        int gm = mt * 128 + mloc;
        if (gm < Me) {
          int t = stok[mloc];
          float w = sw[mloc];
          int h = nt * 128 + wn * 32 + nf * 16 + fr;
          unsafeAtomicAdd(&out[(size_t)t * H_DIM + h], w * v[r]);
        }
      }
    }
}

// ---------------------------------------------------------------------------------------
extern "C" void kernel_launch(void* const* d_in, const int* in_sizes, int n_in,
                              void* d_out, int out_size, void* d_ws, size_t ws_size,
                              hipStream_t stream) {
  const float* X = (const float*)d_in[0];
  const float* GW = (const float*)d_in[1];
  const float* Wg = (const float*)d_in[2];
  const float* Wu = (const float*)d_in[3];
  const float* Wd = (const float*)d_in[4];
  float* out = (float*)d_out;
  float* logits = out + (size_t)T_TOK * H_DIM;

  char* ws = (char*)d_ws;
  int* counts = (int*)ws;                       // 256 B
  int* cursor = (int*)(ws + 256);               // 256 B
  int* offsets = (int*)(ws + 512);              // 260 B
  int* sel_e = (int*)(ws + 1024);               // 64 KB
  float* sel_w = (float*)(ws + 1024 + 65536);   // 64 KB
  int* token_of = (int*)(ws + 1024 + 2 * 65536);
  float* weight_of = (float*)(ws + 1024 + 3 * 65536);
  ushort_t* gact = (ushort_t*)(ws + 524288);    // 16384*1024*2 = 32 MB

  hipMemsetAsync(out, 0, (size_t)T_TOK * H_DIM * sizeof(float), stream);
  hipMemsetAsync(ws, 0, 1024, stream);

  router_kernel<<<T_TOK / 4, 256, 0, stream>>>(X, GW, logits);
  topk_kernel<<<T_TOK / 4, 256, 0, stream>>>(logits, counts, sel_e, sel_w);
  scan_kernel<<<1, 64, 0, stream>>>(counts, offsets, cursor);
  assign_kernel<<<(T_TOK * TOPK) / 256, 256, 0, stream>>>(sel_e, sel_w, offsets, cursor,
                                                          token_of, weight_of);
  proj_kernel<0><<<N_EXP * MT * 8, 512, 0, stream>>>(X, Wg, offsets, token_of, gact);
  proj_kernel<1><<<N_EXP * MT * 8, 512, 0, stream>>>(X, Wu, offsets, token_of, gact);
  down_kernel<<<N_EXP * MT * 16, 512, 0, stream>>>(gact, Wd, offsets, token_of,
                                                   weight_of, out);
}

// Round 12
// 850.460 us; speedup vs baseline: 1.0726x; 1.0726x over previous
//
#include <hip/hip_runtime.h>

typedef unsigned short ushort_t;
typedef unsigned int uint_t;

typedef __attribute__((ext_vector_type(8))) __bf16 bf16x8_t;
typedef __attribute__((ext_vector_type(8))) short s16x8;
typedef __attribute__((ext_vector_type(4))) float f32x4;

#define T_TOK 2048
#define H_DIM 2048
#define I_DIM 1024
#define N_EXP 64
#define TOPK 8
#define MT 6         // 128-row m-tiles: covers up to 768 tokens/expert (mean 256)

#define BAR_RAW()  asm volatile("s_barrier" ::: "memory")
#define WAITVM(N)  asm volatile("s_waitcnt vmcnt(" #N ")" ::: "memory")

#define LDS_OFF(p) ((uint_t)(unsigned long long)(p))

// global -> LDS DMA, 16B/lane, dest = ldsoff (wave-uniform) + lane*16; src per-lane.
__device__ __forceinline__ void gl2lds(const void* g, uint_t ldsoff) {
  __builtin_amdgcn_global_load_lds(
      (const __attribute__((address_space(1))) unsigned*)(unsigned long long)(g),
      (__attribute__((address_space(3))) unsigned*)(ldsoff),
      16, 0, 0);
}

__device__ inline f32x4 mfma_bf16(s16x8 a, s16x8 b, f32x4 c) {
  return __builtin_amdgcn_mfma_f32_16x16x32_bf16(
      __builtin_bit_cast(bf16x8_t, a), __builtin_bit_cast(bf16x8_t, b), c, 0, 0, 0);
}

__device__ inline ushort_t f2bf(float f) {
  uint_t u = __float_as_uint(f);
  u += 0x7FFFu + ((u >> 16) & 1u);   // RNE
  return (ushort_t)(u >> 16);
}
__device__ inline uint_t pkbf(float a, float b) {
  uint_t r;
  asm("v_cvt_pk_bf16_f32 %0, %1, %2" : "=v"(r) : "v"(a), "v"(b));
  return r;
}
__device__ inline uint4 pk8v(f32x4 a, f32x4 b) {
  uint4 w;
  w.x = pkbf(a[0], a[1]); w.y = pkbf(a[2], a[3]);
  w.z = pkbf(b[0], b[1]); w.w = pkbf(b[2], b[3]);
  return w;
}

// Read bf16 MFMA fragment from a swizzled fp32 LDS tile (row = 32 floats = 8
// 16B slots, phys slot = logical ^ (row&7)). Verified correct in R6.
__device__ __forceinline__ s16x8 fragB(const float* tile, int R, int q2) {
  int o0 = ((q2 * 2) ^ (R & 7)) << 4;
  int o1 = o0 ^ 16;
  const char* rowp = (const char*)(tile + R * 32);
  f32x4 a = *(const f32x4*)(rowp + o0);
  f32x4 b = *(const f32x4*)(rowp + o1);
  uint4 u = pk8v(a, b);
  return __builtin_bit_cast(s16x8, u);
}

// A-tile (bf16, row = 32 bf16 = 4 slots of 16B): phys slot = logical ^ swzA(row)
__device__ __forceinline__ int swzA(int r) { return (r ^ (r >> 2)) & 3; }

// XCD-chunk swizzle (bijective when nwg % 8 == 0)
__device__ __forceinline__ int xcd_swizzle(int bid, int nwg) {
  int q = nwg >> 3;
  return (bid & 7) * q + (bid >> 3);
}

// ---------------- X fp32 -> bf16 pre-pass ----------------------------------------------
__global__ __launch_bounds__(256) void xcvt_kernel(const float* __restrict__ X,
                                                   ushort_t* __restrict__ Xbf) {
  int idx = (blockIdx.x * 256 + threadIdx.x) * 8;
  f32x4 a = *(const f32x4*)(X + idx);
  f32x4 b = *(const f32x4*)(X + idx + 4);
  *(uint4*)(Xbf + idx) = pk8v(a, b);
}

// ---------------- Router ---------------------------------------------------------------
__global__ __launch_bounds__(256) void router_kernel(const float* __restrict__ X,
                                                     const float* __restrict__ GW,
                                                     float* __restrict__ logits) {
  __shared__ float xs[4][H_DIM];
  int tid = threadIdx.x;
  int t0 = blockIdx.x * 4;
  const float4* src = (const float4*)(X + (size_t)t0 * H_DIM);
  float4* dst = (float4*)(&xs[0][0]);
#pragma unroll
  for (int j = 0; j < 8; ++j) dst[tid + 256 * j] = src[tid + 256 * j];
  __syncthreads();
  int wave = tid >> 6, lane = tid & 63;
  int t = t0 + wave;
  const float4* w = (const float4*)(GW + (size_t)lane * H_DIM);
  const float4* xr = (const float4*)(&xs[wave][0]);
  float acc = 0.f;
  for (int i = 0; i < H_DIM / 4; ++i) {
    float4 a = xr[i];
    float4 b = w[i];
    acc = fmaf(a.x, b.x, acc);
    acc = fmaf(a.y, b.y, acc);
    acc = fmaf(a.z, b.z, acc);
    acc = fmaf(a.w, b.w, acc);
  }
  logits[(size_t)t * N_EXP + lane] = acc;
}

// ---------------- Softmax + top-8 ------------------------------------------------------
__global__ __launch_bounds__(256) void topk_kernel(const float* __restrict__ logits,
                                                   int* __restrict__ counts,
                                                   int* __restrict__ sel_e,
                                                   float* __restrict__ sel_w) {
  int tid = threadIdx.x;
  int wave = tid >> 6, lane = tid & 63;
  int t = blockIdx.x * 4 + wave;
  float l = logits[(size_t)t * N_EXP + lane];
  float m = l;
#pragma unroll
  for (int s = 32; s; s >>= 1) m = fmaxf(m, __shfl_xor(m, s, 64));
  float p = __expf(l - m);
  float sum = p;
#pragma unroll
  for (int s = 32; s; s >>= 1) sum += __shfl_xor(sum, s, 64);
  float prob = p / sum;

  float val = l;
#pragma unroll
  for (int k = 0; k < TOPK; ++k) {
    float bv = val;
    int bi = lane;
#pragma unroll
    for (int s = 32; s; s >>= 1) {
      float ov = __shfl_xor(bv, s, 64);
      int oi = __shfl_xor(bi, s, 64);
      if (ov > bv || (ov == bv && oi < bi)) { bv = ov; bi = oi; }
    }
    float bw = __shfl(prob, bi, 64);
    if (lane == 0) {
      sel_e[t * TOPK + k] = bi;
      sel_w[t * TOPK + k] = bw;
      atomicAdd(&counts[bi], 1);
    }
    if (lane == bi) val = -INFINITY;
  }
}

__global__ void scan_kernel(const int* __restrict__ counts, int* __restrict__ offsets,
                            int* __restrict__ cursor) {
  if (threadIdx.x == 0) {
    int acc = 0;
    for (int e = 0; e < N_EXP; ++e) { offsets[e] = acc; acc += counts[e]; }
    offsets[N_EXP] = acc;
  }
  if (threadIdx.x < N_EXP) cursor[threadIdx.x] = 0;
}

__global__ __launch_bounds__(256) void assign_kernel(const int* __restrict__ sel_e,
                                                     const float* __restrict__ sel_w,
                                                     const int* __restrict__ offsets,
                                                     int* __restrict__ cursor,
                                                     int* __restrict__ token_of,
                                                     float* __restrict__ weight_of) {
  int idx = blockIdx.x * 256 + threadIdx.x;
  int t = idx >> 3;
  int e = sel_e[idx];
  float w = sel_w[idx];
  int r = offsets[e] + atomicAdd(&cursor[e], 1);
  token_of[r] = t;
  weight_of[r] = w;
}

// =======================================================================================
// Fused gate+up: 512 thr, tile 128x128x(2 proj), BK=32, 8 waves (2M x 4N).
// 3-deep gl_lds ring: A (bf16 X, 8KB/stage, 1 DMA/thr) + Bg,Bu (fp32, 16KB/stage,
// 2 DMA/thr each) = 5 DMA/thr/stage. Counted vmcnt(10) = 2 stages in flight
// (~80 KB/CU) across barriers. fp32 B converted at frag-read (fragB).
// LDS = 3*(8+16+16) KB = 120 KB -> 1 block/CU.
// =======================================================================================
__global__ __launch_bounds__(512, 2) void gateup_kernel(const ushort_t* __restrict__ Xbf,
                                                        const float* __restrict__ Wg,
                                                        const float* __restrict__ Wu,
                                                        const int* __restrict__ offsets,
                                                        const int* __restrict__ token_of,
                                                        ushort_t* __restrict__ act) {
  int bid = xcd_swizzle(blockIdx.x, N_EXP * MT * 8);
  int e = bid / (MT * 8);
  int mt = (bid % (MT * 8)) / 8;
  int nt = bid % 8;
  int base = offsets[e];
  int Me = offsets[e + 1] - base;
  if (mt * 128 >= Me) return;

  __shared__ ushort_t As[3][128 * 32];  // 3 x 8 KB, slot swizzle swzA
  __shared__ float Bg[3][128 * 32];     // 3 x 16 KB, slot swizzle row&7
  __shared__ float Bu[3][128 * 32];     // 3 x 16 KB
  __shared__ int stok[128];

  int tid = threadIdx.x;
  if (tid < 128) {
    int gm = mt * 128 + tid;
    stok[tid] = token_of[base + (gm < Me ? gm : Me - 1)];
  }
  __syncthreads();

  int wave = tid >> 6, lane = tid & 63;
  int wm = wave >> 2, wn = wave & 3;

  // ---- DMA source pointers (per lane) ----
  // A: wave chunk = rows 16w..16w+15; lane: row 16w+(lane>>2), slot lane&3.
  int arow = 16 * wave + (lane >> 2);
  int aslot = (lane & 3) ^ swzA(arow);
  const char* aSrc = (const char*)Xbf + (size_t)stok[arow] * (H_DIM * 2) + aslot * 16;
  uint_t aChunk = wave * 1024;
  // B: chunks c = 2w, 2w+1; lane: row 8c+(lane>>3), slot lane&7.
  int brow0 = 8 * (2 * wave) + (lane >> 3);
  int brow1 = brow0 + 8;
  int bs0 = (lane & 7) ^ (brow0 & 7);
  int bs1 = (lane & 7) ^ (brow1 & 7);
  const char* gSrc0 = (const char*)(Wg + ((size_t)e * I_DIM + nt * 128 + brow0) * H_DIM) + bs0 * 16;
  const char* gSrc1 = (const char*)(Wg + ((size_t)e * I_DIM + nt * 128 + brow1) * H_DIM) + bs1 * 16;
  const char* uSrc0 = (const char*)(Wu + ((size_t)e * I_DIM + nt * 128 + brow0) * H_DIM) + bs0 * 16;
  const char* uSrc1 = (const char*)(Wu + ((size_t)e * I_DIM + nt * 128 + brow1) * H_DIM) + bs1 * 16;
  uint_t bChunk0 = (2 * wave) * 1024;
  uint_t bChunk1 = bChunk0 + 1024;
  uint_t ldsA = LDS_OFF(&As[0][0]);
  uint_t ldsG = LDS_OFF(&Bg[0][0]);
  uint_t ldsU = LDS_OFF(&Bu[0][0]);

#define GU_ISSUE(bufb)                                                   \
  {                                                                      \
    gl2lds(aSrc, ldsA + (uint_t)(bufb) * 8192 + aChunk);                 \
    gl2lds(gSrc0, ldsG + (uint_t)(bufb) * 16384 + bChunk0);              \
    gl2lds(gSrc1, ldsG + (uint_t)(bufb) * 16384 + bChunk1);              \
    gl2lds(uSrc0, ldsU + (uint_t)(bufb) * 16384 + bChunk0);              \
    gl2lds(uSrc1, ldsU + (uint_t)(bufb) * 16384 + bChunk1);              \
    aSrc += 64; gSrc0 += 128; gSrc1 += 128; uSrc0 += 128; uSrc1 += 128;  \
  }

  f32x4 accg[4][2], accu[4][2];
#pragma unroll
  for (int i = 0; i < 4; ++i)
#pragma unroll
    for (int j = 0; j < 2; ++j) { accg[i][j] = (f32x4)0.f; accu[i][j] = (f32x4)0.f; }

  int fr = lane & 15, q2 = lane >> 4;
  const int NK = H_DIM / 32;  // 64

  GU_ISSUE(0);
  GU_ISSUE(1);
  int bc = 0, bt = 2;

  for (int k = 0; k < NK; ++k) {
    BAR_RAW();  // all waves done computing buf[(k-1)%3] (= refill target)
    if (k + 2 < NK) {
      GU_ISSUE(bt);
      WAITVM(10);        // stage k landed (my portion); 2 stages stay in flight
    } else if (k + 2 == NK) {
      WAITVM(5);
    } else {
      WAITVM(0);
    }
    BAR_RAW();  // all waves' portions of stage k landed -> tile complete

    const ushort_t* Ab = &As[0][0] + bc * 4096;
    const float* Gb = &Bg[0][0] + bc * 4096;
    const float* Ub = &Bu[0][0] + bc * 4096;

    s16x8 af[4], bg[2], bu[2];
#pragma unroll
    for (int mf = 0; mf < 4; ++mf) {
      int R = wm * 64 + mf * 16 + fr;
      af[mf] = *(const s16x8*)&Ab[R * 32 + ((q2 ^ swzA(R)) * 8)];
    }
#pragma unroll
    for (int nf = 0; nf < 2; ++nf) {
      int R = wn * 32 + nf * 16 + fr;
      bg[nf] = fragB(Gb, R, q2);
      bu[nf] = fragB(Ub, R, q2);
    }
    __builtin_amdgcn_s_setprio(1);
#pragma unroll
    for (int mf = 0; mf < 4; ++mf)
#pragma unroll
      for (int nf = 0; nf < 2; ++nf) {
        accg[mf][nf] = mfma_bf16(af[mf], bg[nf], accg[mf][nf]);
        accu[mf][nf] = mfma_bf16(af[mf], bu[nf], accu[mf][nf]);
      }
    __builtin_amdgcn_s_setprio(0);

    bc = (bc == 2) ? 0 : bc + 1;
    bt = (bt == 2) ? 0 : bt + 1;
  }

  // epilogue: act = silu(g)*u -> bf16
#pragma unroll
  for (int mf = 0; mf < 4; ++mf)
#pragma unroll
    for (int nf = 0; nf < 2; ++nf) {
      f32x4 g = accg[mf][nf], u = accu[mf][nf];
#pragma unroll
      for (int r = 0; r < 4; ++r) {
        int gm = mt * 128 + wm * 64 + mf * 16 + q2 * 4 + r;
        if (gm < Me) {
          float gv = g[r], uv = u[r];
          float s = gv / (1.f + __expf(-gv));
          int col = nt * 128 + wn * 32 + nf * 16 + fr;
          act[(size_t)(base + gm) * I_DIM + col] = f2bf(s * uv);
        }
      }
    }
#undef GU_ISSUE
}

// =======================================================================================
// Down: same ring, A = act (bf16, 1 DMA/thr), B = Wd (fp32, 2 DMA/thr) = 3/stage.
// vmcnt(6) steady. LDS = 3*(8+16) KB = 72 KB -> 2 blocks/CU.
// =======================================================================================
__global__ __launch_bounds__(512, 4) void down_kernel(const ushort_t* __restrict__ act,
                                                      const float* __restrict__ Wd,
                                                      const int* __restrict__ offsets,
                                                      const int* __restrict__ token_of,
                                                      const float* __restrict__ weight_of,
                                                      float* __restrict__ out) {
  int bid = xcd_swizzle(blockIdx.x, N_EXP * MT * 16);
  int e = bid / (MT * 16);
  int mt = (bid % (MT * 16)) / 16;
  int nt = bid % 16;
  int base = offsets[e];
  int Me = offsets[e + 1] - base;
  if (mt * 128 >= Me) return;

  __shared__ ushort_t As[3][128 * 32];  // 3 x 8 KB
  __shared__ float Bs[3][128 * 32];     // 3 x 16 KB
  __shared__ int stok[128];
  __shared__ float sw[128];

  int tid = threadIdx.x;
  if (tid < 128) {
    int gm = mt * 128 + tid;
    int ok = gm < Me;
    stok[tid] = token_of[base + (ok ? gm : Me - 1)];
    sw[tid] = ok ? weight_of[base + gm] : 0.f;
  }
  __syncthreads();

  int wave = tid >> 6, lane = tid & 63;
  int wm = wave >> 2, wn = wave & 3;

  int arow = 16 * wave + (lane >> 2);
  int aslot = (lane & 3) ^ swzA(arow);
  int agm = mt * 128 + arow;
  if (agm >= Me) agm = Me - 1;
  const char* aSrc = (const char*)act + (size_t)(base + agm) * (I_DIM * 2) + aslot * 16;
  uint_t aChunk = wave * 1024;

  int brow0 = 8 * (2 * wave) + (lane >> 3);
  int brow1 = brow0 + 8;
  int bs0 = (lane & 7) ^ (brow0 & 7);
  int bs1 = (lane & 7) ^ (brow1 & 7);
  const char* bSrc0 = (const char*)(Wd + ((size_t)e * H_DIM + nt * 128 + brow0) * I_DIM) + bs0 * 16;
  const char* bSrc1 = (const char*)(Wd + ((size_t)e * H_DIM + nt * 128 + brow1) * I_DIM) + bs1 * 16;
  uint_t bChunk0 = (2 * wave) * 1024;
  uint_t bChunk1 = bChunk0 + 1024;
  uint_t ldsA = LDS_OFF(&As[0][0]);
  uint_t ldsB = LDS_OFF(&Bs[0][0]);

#define DN_ISSUE(bufb)                                                   \
  {                                                                      \
    gl2lds(aSrc, ldsA + (uint_t)(bufb) * 8192 + aChunk);                 \
    gl2lds(bSrc0, ldsB + (uint_t)(bufb) * 16384 + bChunk0);              \
    gl2lds(bSrc1, ldsB + (uint_t)(bufb) * 16384 + bChunk1);              \
    aSrc += 64; bSrc0 += 128; bSrc1 += 128;                              \
  }

  f32x4 acc[4][2];
#pragma unroll
  for (int i = 0; i < 4; ++i)
#pragma unroll
    for (int j = 0; j < 2; ++j) acc[i][j] = (f32x4)0.f;

  int fr = lane & 15, q2 = lane >> 4;
  const int NK = I_DIM / 32;  // 32

  DN_ISSUE(0);
  DN_ISSUE(1);
  int bc = 0, bt = 2;

  for (int k = 0; k < NK; ++k) {
    BAR_RAW();
    if (k + 2 < NK) {
      DN_ISSUE(bt);
      WAITVM(6);
    } else if (k + 2 == NK) {
      WAITVM(3);
    } else {
      WAITVM(0);
    }
    BAR_RAW();

    const ushort_t* Ab = &As[0][0] + bc * 4096;
    const float* Bb = &Bs[0][0] + bc * 4096;

    s16x8 af[4], bf[2];
#pragma unroll
    for (int mf = 0; mf < 4; ++mf) {
      int R = wm * 64 + mf * 16 + fr;
      af[mf] = *(const s16x8*)&Ab[R * 32 + ((q2 ^ swzA(R)) * 8)];
    }
#pragma unroll
    for (int nf = 0; nf < 2; ++nf) {
      int R = wn * 32 + nf * 16 + fr;
      bf[nf] = fragB(Bb, R, q2);
    }
    __builtin_amdgcn_s_setprio(1);
#pragma unroll
    for (int mf = 0; mf < 4; ++mf)
#pragma unroll
      for (int nf = 0; nf < 2; ++nf)
        acc[mf][nf] = mfma_bf16(af[mf], bf[nf], acc[mf][nf]);
    __builtin_amdgcn_s_setprio(0);

    bc = (bc == 2) ? 0 : bc + 1;
    bt = (bt == 2) ? 0 : bt + 1;
  }

#pragma unroll
  for (int mf = 0; mf < 4; ++mf)
#pragma unroll
    for (int nf = 0; nf < 2; ++nf) {
      f32x4 v = acc[mf][nf];
#pragma unroll
      for (int r = 0; r < 4; ++r) {
        int mloc = wm * 64 + mf * 16 + q2 * 4 + r;
        int gm = mt * 128 + mloc;
        if (gm < Me) {
          int t = stok[mloc];
          float w = sw[mloc];
          int h = nt * 128 + wn * 32 + nf * 16 + fr;
          unsafeAtomicAdd(&out[(size_t)t * H_DIM + h], w * v[r]);
        }
      }
    }
#undef DN_ISSUE
}

// ---------------------------------------------------------------------------------------
extern "C" void kernel_launch(void* const* d_in, const int* in_sizes, int n_in,
                              void* d_out, int out_size, void* d_ws, size_t ws_size,
                              hipStream_t stream) {
  const float* X = (const float*)d_in[0];
  const float* GW = (const float*)d_in[1];
  const float* Wg = (const float*)d_in[2];
  const float* Wu = (const float*)d_in[3];
  const float* Wd = (const float*)d_in[4];
  float* out = (float*)d_out;
  float* logits = out + (size_t)T_TOK * H_DIM;

  char* ws = (char*)d_ws;
  int* counts = (int*)ws;                          // 256 B
  int* cursor = (int*)(ws + 256);                  // 256 B
  int* offsets = (int*)(ws + 512);                 // 260 B
  int* sel_e = (int*)(ws + 1024);                  // 64 KB
  float* sel_w = (float*)(ws + 1024 + 65536);      // 64 KB
  int* token_of = (int*)(ws + 1024 + 2 * 65536);
  float* weight_of = (float*)(ws + 1024 + 3 * 65536);
  ushort_t* Xbf = (ushort_t*)(ws + 524288);        // 8 MB
  ushort_t* gact = (ushort_t*)(ws + 524288 + 8388608);  // 32 MB

  hipMemsetAsync(out, 0, (size_t)T_TOK * H_DIM * sizeof(float), stream);
  hipMemsetAsync(ws, 0, 1024, stream);

  xcvt_kernel<<<(T_TOK * H_DIM) / (256 * 8), 256, 0, stream>>>(X, Xbf);
  router_kernel<<<T_TOK / 4, 256, 0, stream>>>(X, GW, logits);
  topk_kernel<<<T_TOK / 4, 256, 0, stream>>>(logits, counts, sel_e, sel_w);
  scan_kernel<<<1, 64, 0, stream>>>(counts, offsets, cursor);
  assign_kernel<<<(T_TOK * TOPK) / 256, 256, 0, stream>>>(sel_e, sel_w, offsets, cursor,
                                                          token_of, weight_of);
  gateup_kernel<<<N_EXP * MT * 8, 512, 0, stream>>>(Xbf, Wg, Wu, offsets, token_of, gact);
  down_kernel<<<N_EXP * MT * 16, 512, 0, stream>>>(gact, Wd, offsets, token_of,
                                                   weight_of, out);
}